// Round 1
// baseline (203.731 us; speedup 1.0000x reference)
//
#include <hip/hip_runtime.h>
#include <math.h>

#define K_SIZE 5
#define PAD 2
#define DEPTH_MAX 192.0f
#define S_NUM 15

// Fixed problem shape (from reference setup_inputs):
#define B_DIM 2
#define C_DIM 32
#define H_DIM 256
#define W_DIM 512

__global__ __launch_bounds__(256) void adaptive_sample_kernel(
    const float* __restrict__ depth,      // [B,1,H,W]
    const float* __restrict__ features,   // [B,C,H,W]
    const float* __restrict__ guide,      // [B,H,W,25]
    const int*   __restrict__ sample_idx, // [15]
    float*       __restrict__ out)        // [B,C,H,W]
{
    const int p = blockIdx.x * blockDim.x + threadIdx.x;
    const int total = B_DIM * H_DIM * W_DIM;
    if (p >= total) return;

    const int x = p % W_DIM;
    const int y = (p / W_DIM) % H_DIM;
    const int b = p / (W_DIM * H_DIM);

    // ---- sample indices (wave-uniform -> scalar loads) ----
    int sidx[S_NUM];
#pragma unroll
    for (int s = 0; s < S_NUM; ++s) sidx[s] = sample_idx[s];

    // ---- gaussian positional weights, normalized ----
    float posw[S_NUM];
    float psum = 0.f;
#pragma unroll
    for (int s = 0; s < S_NUM; ++s) {
        const float px = (float)(sidx[s] % K_SIZE);
        const float py = (float)(sidx[s] / K_SIZE);
        const float dx = px - (float)(K_SIZE / 2);
        const float dy = py - (float)(K_SIZE / 2);
        const float dis = sqrtf(dx * dx + dy * dy);
        posw[s] = expf(-0.5f * dis);
        psum += posw[s];
    }
    const float inv_psum = 1.f / psum;

    // ---- raw weights: valid(depth@tap) * pos_w * guide(center, idx) ----
    float raw[S_NUM];
    int   off[S_NUM];    // feature offset from center, 0 if OOB
    float inb_f[S_NUM];  // 1 if tap in-bounds else 0
    const int gbase = ((b * H_DIM + y) * W_DIM + x) * (K_SIZE * K_SIZE);
    const int dbase = b * H_DIM * W_DIM;
#pragma unroll
    for (int s = 0; s < S_NUM; ++s) {
        const int dy = sidx[s] / K_SIZE - PAD;
        const int dx = sidx[s] % K_SIZE - PAD;
        const int yy = y + dy;
        const int xx = x + dx;
        const bool inb = (yy >= 0) & (yy < H_DIM) & (xx >= 0) & (xx < W_DIM);
        float v = 0.f;
        if (inb) {
            const float d = depth[dbase + yy * W_DIM + xx];
            v = (d > 0.f && d < DEPTH_MAX) ? 1.f : 0.f;
        }
        const float g = guide[gbase + sidx[s]];
        raw[s]   = v * (posw[s] * inv_psum) * g;
        off[s]   = inb ? (dy * W_DIM + dx) : 0;
        inb_f[s] = inb ? 1.f : 0.f;
    }

    // ---- softmax over the 15 samples (matches jax.nn.softmax exactly) ----
    float m = raw[0];
#pragma unroll
    for (int s = 1; s < S_NUM; ++s) m = fmaxf(m, raw[s]);
    float esum = 0.f;
    float wgt[S_NUM];
#pragma unroll
    for (int s = 0; s < S_NUM; ++s) {
        wgt[s] = expf(raw[s] - m);
        esum += wgt[s];
    }
    const float inv_esum = 1.f / esum;
#pragma unroll
    for (int s = 0; s < S_NUM; ++s) {
        // OOB taps gather zero-padded features -> contribution 0; fold the
        // mask into the weight so the channel loop is branch-free.
        wgt[s] = wgt[s] * inv_esum * inb_f[s];
    }

    // ---- weighted accumulation over channels ----
    const size_t hw = (size_t)H_DIM * W_DIM;
    const float* fbase = features + (size_t)b * C_DIM * hw + (size_t)y * W_DIM + x;
    float*       obase = out      + (size_t)b * C_DIM * hw + (size_t)y * W_DIM + x;
#pragma unroll 4
    for (int c = 0; c < C_DIM; ++c) {
        float acc = 0.f;
#pragma unroll
        for (int s = 0; s < S_NUM; ++s) {
            acc = fmaf(fbase[off[s]], wgt[s], acc);
        }
        *obase = acc;
        fbase += hw;
        obase += hw;
    }
}

extern "C" void kernel_launch(void* const* d_in, const int* in_sizes, int n_in,
                              void* d_out, int out_size, void* d_ws, size_t ws_size,
                              hipStream_t stream) {
    const float* depth      = (const float*)d_in[0];
    const float* features   = (const float*)d_in[1];
    const float* guide      = (const float*)d_in[2];
    const int*   sample_idx = (const int*)d_in[3];

    float* out = (float*)d_out;
    const size_t feat_elems = (size_t)B_DIM * C_DIM * H_DIM * W_DIM;

    const int total = B_DIM * H_DIM * W_DIM;
    const int block = 256;
    const int grid = (total + block - 1) / block;
    adaptive_sample_kernel<<<grid, block, 0, stream>>>(depth, features, guide,
                                                       sample_idx, out);

    // Output 1: passthrough copy of features.
    hipMemcpyAsync(out + feat_elems, features, feat_elems * sizeof(float),
                   hipMemcpyDeviceToDevice, stream);
}